// Round 7
// baseline (14.370 us; speedup 1.0000x reference)
//
#include <hip/hip_runtime.h>

#define TPB 512

typedef float v2f __attribute__((ext_vector_type(2)));

__device__ __forceinline__ float frelu(float v) { return v > 0.f ? v : 0.f; }

// One block per needed output position (38 total).
// Blocks 0..31: (b=p>>2, h2=(p&3)*20, w2=0), d2 channels {1,161,321}.
// Blocks 32..37: head4 positions, single d2 channel.
//
//  P0: issue ALL global loads (regs + LDS), incl. k2 -> regs of thr 256-511
//  P1: conv1 (threads 0..287, column-major pos map so wave0 self-skips when
//      w2==0; oc-tile packed as 2x float2 -> v_pk_fma_f32, half the issue)
//  P2: conv2 partials (threads 256..511, k2 in registers, pk-FMA)
//  P3: ic-reduce + bias + relu + pool2 (threads 0..127 + shfl_xor max)
//  P4: dense1 32->300 (register weights)
//  P5: dense2 (wave-per-channel reduce, d2 weights in registers)
//  P6: heads (register weights)
__global__ __launch_bounds__(TPB, 1) void hyper_kernel(
    const float* __restrict__ x,    // (8,640,640,3)
    const float* __restrict__ k1,   // (5,5,3,32)
    const float* __restrict__ b1,   // (32)
    const float* __restrict__ k2,   // (5,5,32,32)
    const float* __restrict__ b2,   // (32)
    const float* __restrict__ d1k,  // (32,300)
    const float* __restrict__ d1b,  // (300)
    const float* __restrict__ d2k,  // (300,1340)
    const float* __restrict__ d2b,  // (1340)
    const float* __restrict__ w1k, const float* __restrict__ w1b,  // 2001
    const float* __restrict__ w2k, const float* __restrict__ w2b,  // 801
    const float* __restrict__ w3k, const float* __restrict__ w3b,  // 321
    const float* __restrict__ w4k, const float* __restrict__ w4b,  // 65
    float* __restrict__ out)        // 100326
{
    __shared__ float xs[3 * 676];        // channel-planar x patch [ic][26][26]
    __shared__ float k1s[2400];
    __shared__ float p1[36 * 32];
    __shared__ float part[32 * 132];     // [ic][pos*33 + oc]
    __shared__ float zz[32];
    __shared__ float aa[300];
    __shared__ float yy[3];

    const int p   = blockIdx.x;
    const int tid = threadIdx.x;

    int b, h2, w2, nch, ch0, ch1, ch2;
    if (p < 32) {
        b = p >> 2; h2 = (p & 3) * 20; w2 = 0;
        nch = 3; ch0 = 1; ch1 = 161; ch2 = 321;
    } else {
        const int qb[6] = {0, 1, 2, 4, 5, 6};
        const int qh[6] = {0, 26, 53, 0, 26, 53};
        const int qw[6] = {0, 53, 26, 0, 53, 26};
        const int qc[6] = {481, 491, 501, 481, 491, 501};
        const int q = p - 32;
        b = qb[q]; h2 = qh[q]; w2 = qw[q];
        nch = 1; ch0 = qc[q]; ch1 = 0; ch2 = 0;
    }

    // ================= P0: issue ALL independent global loads =============
    // dense1 weights+bias (thread j owns output j)
    float rd1[32];
    float d1breg = 0.f;
    if (tid < 300) {
#pragma unroll
        for (int c = 0; c < 32; ++c) rd1[c] = d1k[c * 300 + tid];
        d1breg = d1b[tid];
    }

    // conv1 bias (4 oc per conv1 thread)
    float4 b1reg = make_float4(0.f, 0.f, 0.f, 0.f);
    if (tid < 288) b1reg = *(const float4*)&b1[(tid & 7) * 4];

    // conv2 bias (P3 threads)
    float b2reg = (tid < 128) ? b2[tid >> 2] : 0.f;

    // dense2 gather columns + bias -> P5 thread registers
    float d2reg[5] = {0.f, 0.f, 0.f, 0.f, 0.f};
    float d2breg = 0.f;
    if (tid < 192) {
        const int wv = tid >> 6;
        if (wv < nch) {
            const int ch = (wv == 0) ? ch0 : ((wv == 1) ? ch1 : ch2);
#pragma unroll
            for (int u = 0; u < 5; ++u) {
                const int j = (tid & 63) + 64 * u;
                if (j < 300) d2reg[u] = d2k[j * 1340 + ch];
            }
            d2breg = d2b[ch];
        }
    }

    // k2 -> registers of the P2 threads (256..511): 25 float4 each
    float4 kreg[25];
    if (tid >= 256) {
        const int t = tid - 256;
        const float4* k2v = (const float4*)k2 + (t >> 3) * 8 + (t & 7);
#pragma unroll
        for (int tap = 0; tap < 25; ++tap) kreg[tap] = k2v[tap * 256];
    }

    // head weights/biases -> registers
    float hk1[4], hb1[4], hk2[2], hb2[2], hk3 = 0.f, hb3 = 0.f, hk4 = 0.f, hb4 = 0.f;
    if (p < 32) {
#pragma unroll
        for (int u = 0; u < 4; ++u) {
            const int i = tid + u * TPB;
            if (i < 2001) { hk1[u] = w1k[i]; hb1[u] = w1b[i]; }
        }
#pragma unroll
        for (int u = 0; u < 2; ++u) {
            const int i = tid + u * TPB;
            if (i < 801) { hk2[u] = w2k[i]; hb2[u] = w2b[i]; }
        }
        if (tid < 321) { hk3 = w3k[tid]; hb3 = w3b[tid]; }
    } else {
        if (tid < 65) { hk4 = w4k[tid]; hb4 = w4b[tid]; }
    }

    // x patch -> LDS, channel-planar (zero-padded)
    const int r0 = 8 * h2 - 10;
    const int c0 = 8 * w2 - 10;
    for (int idx = tid; idx < 3 * 676; idx += TPB) {
        const int ic  = idx / 676;
        const int rem = idx - ic * 676;
        const int row = rem / 26, col = rem - (rem / 26) * 26;
        const int gh = r0 + row, gw = c0 + col;
        float v = 0.f;
        if ((unsigned)gh < 640u && (unsigned)gw < 640u)
            v = x[((b * 640 + gh) * 640 + gw) * 3 + ic];
        xs[idx] = v;
    }
    for (int i = tid; i < 2400; i += TPB) k1s[i] = k1[i];
    __syncthreads();   // sync1 — one round trip for everything above

    // ===== P1: conv1 (threads 0..287, column-major pos, pk-FMA) ===========
    if (tid < 288) {
        const int posp = tid >> 3;       // 0..35, COLUMN-major
        const int ocg  = tid & 7;        // 4 oc per thread (2x v2f)
        const int wp6 = posp / 6, hp6 = posp - wp6 * 6;
        const int pos = hp6 * 6 + wp6;   // canonical row-major index into p1
        const int hp = 2 * h2 - 2 + hp6;
        const int wp = 2 * w2 - 2 + wp6;
        float r00 = 0.f, r01 = 0.f, r10 = 0.f, r11 = 0.f;
        if ((unsigned)hp < 160u && (unsigned)wp < 160u) {
            const v2f b1a = {b1reg.x, b1reg.y};
            const v2f b1b = {b1reg.z, b1reg.w};
            v2f accA[4], accB[4];        // [tap], oc-pair A=(0,1) B=(2,3)
#pragma unroll
            for (int t4 = 0; t4 < 4; ++t4) { accA[t4] = b1a; accB[t4] = b1b; }
            const int rbase = 4 * hp6, cbase = 4 * wp6;
#pragma unroll
            for (int dh = 0; dh < 5; ++dh) {
#pragma unroll
                for (int ic = 0; ic < 3; ++ic) {
                    const float* rp0 = &xs[ic * 676 + (rbase + dh) * 26 + cbase];
                    const float2 a0 = *(const float2*)(rp0);
                    const float2 a2 = *(const float2*)(rp0 + 2);
                    const float2 a4 = *(const float2*)(rp0 + 4);
                    const float2 c0_ = *(const float2*)(rp0 + 26);
                    const float2 c2_ = *(const float2*)(rp0 + 28);
                    const float2 c4_ = *(const float2*)(rp0 + 30);
                    const float xr0[6] = {a0.x, a0.y, a2.x, a2.y, a4.x, a4.y};
                    const float xr1[6] = {c0_.x, c0_.y, c2_.x, c2_.y, c4_.x, c4_.y};
#pragma unroll
                    for (int dw = 0; dw < 5; ++dw) {
                        const float4 kv = *(const float4*)&k1s[(((dh * 5 + dw) * 3 + ic) << 5) + (ocg << 2)];
                        const v2f ka = {kv.x, kv.y};
                        const v2f kb = {kv.z, kv.w};
                        const float x00 = xr0[dw], x01 = xr0[dw + 1];
                        const float x10 = xr1[dw], x11 = xr1[dw + 1];
                        accA[0] += x00 * ka; accB[0] += x00 * kb;
                        accA[1] += x01 * ka; accB[1] += x01 * kb;
                        accA[2] += x10 * ka; accB[2] += x10 * kb;
                        accA[3] += x11 * ka; accB[3] += x11 * kb;
                    }
                }
            }
            r00 = frelu(fmaxf(fmaxf(accA[0].x, accA[1].x), fmaxf(accA[2].x, accA[3].x)));
            r01 = frelu(fmaxf(fmaxf(accA[0].y, accA[1].y), fmaxf(accA[2].y, accA[3].y)));
            r10 = frelu(fmaxf(fmaxf(accB[0].x, accB[1].x), fmaxf(accB[2].x, accB[3].x)));
            r11 = frelu(fmaxf(fmaxf(accB[0].y, accB[1].y), fmaxf(accB[2].y, accB[3].y)));
        }
        *(float4*)&p1[pos * 32 + ocg * 4] = make_float4(r00, r01, r10, r11);
    }
    __syncthreads();   // sync2 — p1 ready

    // ===== P2: conv2 partials (threads 256..511, k2 in regs, pk-FMA) ======
    if (tid >= 256) {
        const int t   = tid - 256;
        const int ic  = t >> 3;
        const int ocg = t & 7;
        v2f accA[4], accB[4];            // [pos], oc-pair A=(0,1) B=(2,3)
#pragma unroll
        for (int q = 0; q < 4; ++q) { accA[q] = (v2f){0.f, 0.f}; accB[q] = (v2f){0.f, 0.f}; }
#pragma unroll
        for (int dh = 0; dh < 5; ++dh)
#pragma unroll
            for (int dw = 0; dw < 5; ++dw) {
                const float4 kv = kreg[dh * 5 + dw];
                const v2f ka = {kv.x, kv.y};
                const v2f kb = {kv.z, kv.w};
                float pv[4];
#pragma unroll
                for (int pos = 0; pos < 4; ++pos) {
                    const int dy = pos >> 1, dx = pos & 1;
                    pv[pos] = p1[((dy + dh) * 6 + (dx + dw)) * 32 + ic];
                }
#pragma unroll
                for (int pos = 0; pos < 4; ++pos) {
                    accA[pos] += pv[pos] * ka;
                    accB[pos] += pv[pos] * kb;
                }
            }
#pragma unroll
        for (int pos = 0; pos < 4; ++pos) {
            float* dst = &part[ic * 132 + pos * 33 + ocg * 4];
            dst[0] = accA[pos].x; dst[1] = accA[pos].y;
            dst[2] = accB[pos].x; dst[3] = accB[pos].y;
        }
    }
    __syncthreads();   // sync3

    // ===== P3: ic-reduce + bias + relu + pool2 (128 thr + shfl max) =======
    if (tid < 128) {
        const int oc  = tid >> 2;
        const int pos = tid & 3;         // shfl_xor partner stays in-wave
        float s = b2reg;
        for (int ic = 0; ic < 32; ++ic)
            s += part[ic * 132 + pos * 33 + oc];
        float v = frelu(s);
        v = fmaxf(v, __shfl_xor(v, 1));
        v = fmaxf(v, __shfl_xor(v, 2));
        if (pos == 0) zz[oc] = v;
    }
    __syncthreads();   // sync4

    // ===== P4: dense1 32->300 (register weights) ===========================
    if (tid < 300) {
        float acc = d1breg;
#pragma unroll
        for (int c = 0; c < 32; ++c)
            acc += zz[c] * rd1[c];
        aa[tid] = frelu(acc);
    }
    __syncthreads();   // sync5

    // ===== P5: dense2 (wave-per-channel reduce, weights in regs) ===========
    if (tid < 64 * nch) {
        const int wv = tid >> 6, lane = tid & 63;
        float s = 0.f;
#pragma unroll
        for (int u = 0; u < 5; ++u) {
            const int j = lane + 64 * u;
            if (j < 300) s += aa[j] * d2reg[u];
        }
        for (int off = 32; off > 0; off >>= 1)
            s += __shfl_down(s, off);
        if (lane == 0) yy[wv] = frelu(s + d2breg);
    }
    __syncthreads();   // sync6

    // ===== P6: heads (register weights) ====================================
    if (p < 32) {
        const float y1 = yy[0], y2 = yy[1], y3 = yy[2];
#pragma unroll
        for (int u = 0; u < 4; ++u) {
            const int i = tid + u * TPB;
            if (i < 2001) out[p * 2001 + i] = frelu(y1 * hk1[u] + hb1[u]);
        }
#pragma unroll
        for (int u = 0; u < 2; ++u) {
            const int i = tid + u * TPB;
            if (i < 801) out[64032 + p * 801 + i] = frelu(y2 * hk2[u] + hb2[u]);
        }
        if (tid < 321) out[89664 + p * 321 + tid] = frelu(y3 * hk3 + hb3);
    } else {
        const float y4 = yy[0];
        if (tid < 65) out[99936 + (p - 32) * 65 + tid] = frelu(y4 * hk4 + hb4);
    }
}

extern "C" void kernel_launch(void* const* d_in, const int* in_sizes, int n_in,
                              void* d_out, int out_size, void* d_ws, size_t ws_size,
                              hipStream_t stream) {
    (void)in_sizes; (void)n_in; (void)d_ws; (void)ws_size; (void)out_size;
    const float* x   = (const float*)d_in[0];
    const float* k1  = (const float*)d_in[1];
    const float* b1  = (const float*)d_in[2];
    const float* k2  = (const float*)d_in[3];
    const float* b2  = (const float*)d_in[4];
    const float* d1k = (const float*)d_in[5];
    const float* d1b = (const float*)d_in[6];
    const float* d2k = (const float*)d_in[7];
    const float* d2b = (const float*)d_in[8];
    const float* w1k = (const float*)d_in[9];
    const float* w1b = (const float*)d_in[10];
    const float* w2k = (const float*)d_in[11];
    const float* w2b = (const float*)d_in[12];
    const float* w3k = (const float*)d_in[13];
    const float* w3b = (const float*)d_in[14];
    const float* w4k = (const float*)d_in[15];
    const float* w4b = (const float*)d_in[16];

    hyper_kernel<<<38, TPB, 0, stream>>>(
        x, k1, b1, k2, b2, d1k, d1b, d2k, d2b,
        w1k, w1b, w2k, w2b, w3k, w3b, w4k, w4b,
        (float*)d_out);
}

// Round 8
// 14.241 us; speedup vs baseline: 1.0091x; 1.0091x over previous
//
#include <hip/hip_runtime.h>

#define TPB 512

__device__ __forceinline__ float frelu(float v) { return v > 0.f ? v : 0.f; }

// One block per needed output position (38 total).
// Blocks 0..31: (b=p>>2, h2=(p&3)*20, w2=0), d2 channels {1,161,321}.
// Blocks 32..37: head4 positions, single d2 channel.
//
//  P0: issue ALL global loads (regs + LDS), incl. k2 -> regs of thr 256-511
//  P1: conv1 (threads 0..287, COLUMN-MAJOR pos map: wave0 self-skips when
//      w2==0 since wp6 in {0,1} is out-of-range -> each SIMD issues exactly
//      one conv1 stream)
//  P2: conv2 partials (threads 256..511, k2 already in registers)
//  P3: ic-reduce + bias + relu + pool2 (threads 0..127 + shfl_xor max)
//  P4: dense1 32->300 (register weights)
//  P5: dense2 (wave-per-channel reduce, d2 weights in registers)
//  P6: heads (register weights)
__global__ __launch_bounds__(TPB, 1) void hyper_kernel(
    const float* __restrict__ x,    // (8,640,640,3)
    const float* __restrict__ k1,   // (5,5,3,32)
    const float* __restrict__ b1,   // (32)
    const float* __restrict__ k2,   // (5,5,32,32)
    const float* __restrict__ b2,   // (32)
    const float* __restrict__ d1k,  // (32,300)
    const float* __restrict__ d1b,  // (300)
    const float* __restrict__ d2k,  // (300,1340)
    const float* __restrict__ d2b,  // (1340)
    const float* __restrict__ w1k, const float* __restrict__ w1b,  // 2001
    const float* __restrict__ w2k, const float* __restrict__ w2b,  // 801
    const float* __restrict__ w3k, const float* __restrict__ w3b,  // 321
    const float* __restrict__ w4k, const float* __restrict__ w4b,  // 65
    float* __restrict__ out)        // 100326
{
    __shared__ float xs[3 * 676];        // channel-planar x patch [ic][26][26]
    __shared__ float k1s[2400];
    __shared__ float p1[36 * 32];
    __shared__ float part[32 * 132];     // [ic][pos*33 + oc]
    __shared__ float zz[32];
    __shared__ float aa[300];
    __shared__ float yy[3];

    const int p   = blockIdx.x;
    const int tid = threadIdx.x;

    int b, h2, w2, nch, ch0, ch1, ch2;
    if (p < 32) {
        b = p >> 2; h2 = (p & 3) * 20; w2 = 0;
        nch = 3; ch0 = 1; ch1 = 161; ch2 = 321;
    } else {
        const int qb[6] = {0, 1, 2, 4, 5, 6};
        const int qh[6] = {0, 26, 53, 0, 26, 53};
        const int qw[6] = {0, 53, 26, 0, 53, 26};
        const int qc[6] = {481, 491, 501, 481, 491, 501};
        const int q = p - 32;
        b = qb[q]; h2 = qh[q]; w2 = qw[q];
        nch = 1; ch0 = qc[q]; ch1 = 0; ch2 = 0;
    }

    // ================= P0: issue ALL independent global loads =============
    // dense1 weights+bias (thread j owns output j)
    float rd1[32];
    float d1breg = 0.f;
    if (tid < 300) {
#pragma unroll
        for (int c = 0; c < 32; ++c) rd1[c] = d1k[c * 300 + tid];
        d1breg = d1b[tid];
    }

    // conv1 bias (4 oc per conv1 thread)
    float4 b1reg = make_float4(0.f, 0.f, 0.f, 0.f);
    if (tid < 288) b1reg = *(const float4*)&b1[(tid & 7) * 4];

    // conv2 bias (P3 threads)
    float b2reg = (tid < 128) ? b2[tid >> 2] : 0.f;

    // dense2 gather columns + bias -> P5 thread registers
    float d2reg[5] = {0.f, 0.f, 0.f, 0.f, 0.f};
    float d2breg = 0.f;
    if (tid < 192) {
        const int wv = tid >> 6;
        if (wv < nch) {
            const int ch = (wv == 0) ? ch0 : ((wv == 1) ? ch1 : ch2);
#pragma unroll
            for (int u = 0; u < 5; ++u) {
                const int j = (tid & 63) + 64 * u;
                if (j < 300) d2reg[u] = d2k[j * 1340 + ch];
            }
            d2breg = d2b[ch];
        }
    }

    // k2 -> registers of the P2 threads (256..511): 25 float4 each
    float4 kreg[25];
    if (tid >= 256) {
        const int t = tid - 256;
        const float4* k2v = (const float4*)k2 + (t >> 3) * 8 + (t & 7);
#pragma unroll
        for (int tap = 0; tap < 25; ++tap) kreg[tap] = k2v[tap * 256];
    }

    // head weights/biases -> registers
    float hk1[4], hb1[4], hk2[2], hb2[2], hk3 = 0.f, hb3 = 0.f, hk4 = 0.f, hb4 = 0.f;
    if (p < 32) {
#pragma unroll
        for (int u = 0; u < 4; ++u) {
            const int i = tid + u * TPB;
            if (i < 2001) { hk1[u] = w1k[i]; hb1[u] = w1b[i]; }
        }
#pragma unroll
        for (int u = 0; u < 2; ++u) {
            const int i = tid + u * TPB;
            if (i < 801) { hk2[u] = w2k[i]; hb2[u] = w2b[i]; }
        }
        if (tid < 321) { hk3 = w3k[tid]; hb3 = w3b[tid]; }
    } else {
        if (tid < 65) { hk4 = w4k[tid]; hb4 = w4b[tid]; }
    }

    // x patch -> LDS, channel-planar (zero-padded)
    const int r0 = 8 * h2 - 10;
    const int c0 = 8 * w2 - 10;
    for (int idx = tid; idx < 3 * 676; idx += TPB) {
        const int ic  = idx / 676;
        const int rem = idx - ic * 676;
        const int row = rem / 26, col = rem - (rem / 26) * 26;
        const int gh = r0 + row, gw = c0 + col;
        float v = 0.f;
        if ((unsigned)gh < 640u && (unsigned)gw < 640u)
            v = x[((b * 640 + gh) * 640 + gw) * 3 + ic];
        xs[idx] = v;
    }
    for (int i = tid; i < 2400; i += TPB) k1s[i] = k1[i];
    __syncthreads();   // sync1 — one round trip for everything above

    // ===== P1: conv1 (threads 0..287, column-major pos, 4tap x 4oc) =======
    if (tid < 288) {
        const int posp = tid >> 3;       // 0..35, COLUMN-major
        const int ocg  = tid & 7;        // 4 oc per thread
        const int wp6 = posp / 6, hp6 = posp - wp6 * 6;
        const int pos = hp6 * 6 + wp6;   // canonical row-major index into p1
        const int hp = 2 * h2 - 2 + hp6;
        const int wp = 2 * w2 - 2 + wp6;
        float r00 = 0.f, r01 = 0.f, r10 = 0.f, r11 = 0.f;
        if ((unsigned)hp < 160u && (unsigned)wp < 160u) {
            float acc[4][4];
#pragma unroll
            for (int t4 = 0; t4 < 4; ++t4) {
                acc[t4][0] = b1reg.x; acc[t4][1] = b1reg.y;
                acc[t4][2] = b1reg.z; acc[t4][3] = b1reg.w;
            }
            const int rbase = 4 * hp6, cbase = 4 * wp6;
#pragma unroll
            for (int dh = 0; dh < 5; ++dh) {
#pragma unroll
                for (int ic = 0; ic < 3; ++ic) {
                    const float* rp0 = &xs[ic * 676 + (rbase + dh) * 26 + cbase];
                    const float2 a0 = *(const float2*)(rp0);
                    const float2 a2 = *(const float2*)(rp0 + 2);
                    const float2 a4 = *(const float2*)(rp0 + 4);
                    const float2 c0_ = *(const float2*)(rp0 + 26);
                    const float2 c2_ = *(const float2*)(rp0 + 28);
                    const float2 c4_ = *(const float2*)(rp0 + 30);
                    const float xr0[6] = {a0.x, a0.y, a2.x, a2.y, a4.x, a4.y};
                    const float xr1[6] = {c0_.x, c0_.y, c2_.x, c2_.y, c4_.x, c4_.y};
#pragma unroll
                    for (int dw = 0; dw < 5; ++dw) {
                        const float4 kv = *(const float4*)&k1s[(((dh * 5 + dw) * 3 + ic) << 5) + (ocg << 2)];
                        const float x00 = xr0[dw], x01 = xr0[dw + 1];
                        const float x10 = xr1[dw], x11 = xr1[dw + 1];
                        acc[0][0] += x00 * kv.x; acc[0][1] += x00 * kv.y;
                        acc[0][2] += x00 * kv.z; acc[0][3] += x00 * kv.w;
                        acc[1][0] += x01 * kv.x; acc[1][1] += x01 * kv.y;
                        acc[1][2] += x01 * kv.z; acc[1][3] += x01 * kv.w;
                        acc[2][0] += x10 * kv.x; acc[2][1] += x10 * kv.y;
                        acc[2][2] += x10 * kv.z; acc[2][3] += x10 * kv.w;
                        acc[3][0] += x11 * kv.x; acc[3][1] += x11 * kv.y;
                        acc[3][2] += x11 * kv.z; acc[3][3] += x11 * kv.w;
                    }
                }
            }
            r00 = frelu(fmaxf(fmaxf(acc[0][0], acc[1][0]), fmaxf(acc[2][0], acc[3][0])));
            r01 = frelu(fmaxf(fmaxf(acc[0][1], acc[1][1]), fmaxf(acc[2][1], acc[3][1])));
            r10 = frelu(fmaxf(fmaxf(acc[0][2], acc[1][2]), fmaxf(acc[2][2], acc[3][2])));
            r11 = frelu(fmaxf(fmaxf(acc[0][3], acc[1][3]), fmaxf(acc[2][3], acc[3][3])));
        }
        *(float4*)&p1[pos * 32 + ocg * 4] = make_float4(r00, r01, r10, r11);
    }
    __syncthreads();   // sync2 — p1 ready

    // ===== P2: conv2 partials (threads 256..511, k2 in registers) =========
    if (tid >= 256) {
        const int t   = tid - 256;
        const int ic  = t >> 3;
        const int ocg = t & 7;
        float acc[4][4];
#pragma unroll
        for (int q = 0; q < 4; ++q) { acc[q][0] = acc[q][1] = acc[q][2] = acc[q][3] = 0.f; }
#pragma unroll
        for (int dh = 0; dh < 5; ++dh)
#pragma unroll
            for (int dw = 0; dw < 5; ++dw) {
                const float4 kv = kreg[dh * 5 + dw];
                float pv[4];
#pragma unroll
                for (int pos = 0; pos < 4; ++pos) {
                    const int dy = pos >> 1, dx = pos & 1;
                    pv[pos] = p1[((dy + dh) * 6 + (dx + dw)) * 32 + ic];
                }
#pragma unroll
                for (int pos = 0; pos < 4; ++pos) {
                    acc[pos][0] += pv[pos] * kv.x;
                    acc[pos][1] += pv[pos] * kv.y;
                    acc[pos][2] += pv[pos] * kv.z;
                    acc[pos][3] += pv[pos] * kv.w;
                }
            }
#pragma unroll
        for (int pos = 0; pos < 4; ++pos)
#pragma unroll
            for (int o = 0; o < 4; ++o)
                part[ic * 132 + pos * 33 + ocg * 4 + o] = acc[pos][o];
    }
    __syncthreads();   // sync3

    // ===== P3: ic-reduce + bias + relu + pool2 (128 thr + shfl max) =======
    if (tid < 128) {
        const int oc  = tid >> 2;
        const int pos = tid & 3;         // shfl_xor partner stays in-wave
        float s = b2reg;
        for (int ic = 0; ic < 32; ++ic)
            s += part[ic * 132 + pos * 33 + oc];
        float v = frelu(s);
        v = fmaxf(v, __shfl_xor(v, 1));
        v = fmaxf(v, __shfl_xor(v, 2));
        if (pos == 0) zz[oc] = v;
    }
    __syncthreads();   // sync4

    // ===== P4: dense1 32->300 (register weights) ===========================
    if (tid < 300) {
        float acc = d1breg;
#pragma unroll
        for (int c = 0; c < 32; ++c)
            acc += zz[c] * rd1[c];
        aa[tid] = frelu(acc);
    }
    __syncthreads();   // sync5

    // ===== P5: dense2 (wave-per-channel reduce, weights in regs) ===========
    if (tid < 64 * nch) {
        const int wv = tid >> 6, lane = tid & 63;
        float s = 0.f;
#pragma unroll
        for (int u = 0; u < 5; ++u) {
            const int j = lane + 64 * u;
            if (j < 300) s += aa[j] * d2reg[u];
        }
        for (int off = 32; off > 0; off >>= 1)
            s += __shfl_down(s, off);
        if (lane == 0) yy[wv] = frelu(s + d2breg);
    }
    __syncthreads();   // sync6

    // ===== P6: heads (register weights) ====================================
    if (p < 32) {
        const float y1 = yy[0], y2 = yy[1], y3 = yy[2];
#pragma unroll
        for (int u = 0; u < 4; ++u) {
            const int i = tid + u * TPB;
            if (i < 2001) out[p * 2001 + i] = frelu(y1 * hk1[u] + hb1[u]);
        }
#pragma unroll
        for (int u = 0; u < 2; ++u) {
            const int i = tid + u * TPB;
            if (i < 801) out[64032 + p * 801 + i] = frelu(y2 * hk2[u] + hb2[u]);
        }
        if (tid < 321) out[89664 + p * 321 + tid] = frelu(y3 * hk3 + hb3);
    } else {
        const float y4 = yy[0];
        if (tid < 65) out[99936 + (p - 32) * 65 + tid] = frelu(y4 * hk4 + hb4);
    }
}

extern "C" void kernel_launch(void* const* d_in, const int* in_sizes, int n_in,
                              void* d_out, int out_size, void* d_ws, size_t ws_size,
                              hipStream_t stream) {
    (void)in_sizes; (void)n_in; (void)d_ws; (void)ws_size; (void)out_size;
    const float* x   = (const float*)d_in[0];
    const float* k1  = (const float*)d_in[1];
    const float* b1  = (const float*)d_in[2];
    const float* k2  = (const float*)d_in[3];
    const float* b2  = (const float*)d_in[4];
    const float* d1k = (const float*)d_in[5];
    const float* d1b = (const float*)d_in[6];
    const float* d2k = (const float*)d_in[7];
    const float* d2b = (const float*)d_in[8];
    const float* w1k = (const float*)d_in[9];
    const float* w1b = (const float*)d_in[10];
    const float* w2k = (const float*)d_in[11];
    const float* w2b = (const float*)d_in[12];
    const float* w3k = (const float*)d_in[13];
    const float* w3b = (const float*)d_in[14];
    const float* w4k = (const float*)d_in[15];
    const float* w4b = (const float*)d_in[16];

    hyper_kernel<<<38, TPB, 0, stream>>>(
        x, k1, b1, k2, b2, d1k, d1b, d2k, d2b,
        w1k, w1b, w2k, w2b, w3k, w3b, w4k, w4b,
        (float*)d_out);
}